// Round 8
// baseline (159.123 us; speedup 1.0000x reference)
//
#include <hip/hip_runtime.h>

#define N_SAMP 1024
#define XD     128
#define HID    256

// ---------------------------------------------------------------------------
// Workspace layout (float indices):
//   [0, 1024)            S       per-i sum of exp(T1[i,j]) over j
//   [1024]               T0sum   sum over i of T1[i,i]  (diagonal, sans b2)
//   [1025]               ticket counter (uint bits), last-block-done
//   [2048, 2048+256K)    xpbT    (x @ W1x + b1)^T   [HID][N]  (k-major)
//   [next 256K)          ypT     (y @ W1y)^T        [HID][N]  (k-major)
// S/T0sum/ticket zeroed by gemm_xy every launch (ws is poisoned 0xAA).
// ---------------------------------------------------------------------------

// Kernel 1: the two small GEMMs, writing TRANSPOSED outputs. Thread k owns
// hidden unit k for 4 consecutive rows -> in k-major layout those 4 results
// are contiguous: one float4 store per array. Also zeroes S/T0sum/ticket.
__global__ __launch_bounds__(256) void gemm_xy(
    const float* __restrict__ x, const float* __restrict__ y,
    const float* __restrict__ W1, const float* __restrict__ b1,
    float* __restrict__ xpbT, float* __restrict__ ypT,
    float* __restrict__ S, float* __restrict__ T0sum)
{
    const int k  = threadIdx.x;        // hidden unit 0..255
    const int r0 = blockIdx.x * 4;     // 4 rows per block

    // Zero accumulators (256 blocks x 4 = 1024 S entries; block 0: T0+ticket).
    if (threadIdx.x < 4) S[blockIdx.x * 4 + threadIdx.x] = 0.f;
    if (blockIdx.x == 0 && threadIdx.x == 4) T0sum[0] = 0.f;
    if (blockIdx.x == 0 && threadIdx.x == 5) ((unsigned*)T0sum)[1] = 0u;

    float ax0 = 0.f, ax1 = 0.f, ax2 = 0.f, ax3 = 0.f;
    float ay0 = 0.f, ay1 = 0.f, ay2 = 0.f, ay3 = 0.f;

    #pragma unroll 4
    for (int d = 0; d < XD; ++d) {
        const float wx = W1[d * HID + k];            // coalesced over k
        const float wy = W1[(XD + d) * HID + k];
        ax0 = fmaf(x[(r0 + 0) * XD + d], wx, ax0);   // uniform -> s_load
        ax1 = fmaf(x[(r0 + 1) * XD + d], wx, ax1);
        ax2 = fmaf(x[(r0 + 2) * XD + d], wx, ax2);
        ax3 = fmaf(x[(r0 + 3) * XD + d], wx, ax3);
        ay0 = fmaf(y[(r0 + 0) * XD + d], wy, ay0);
        ay1 = fmaf(y[(r0 + 1) * XD + d], wy, ay1);
        ay2 = fmaf(y[(r0 + 2) * XD + d], wy, ay2);
        ay3 = fmaf(y[(r0 + 3) * XD + d], wy, ay3);
    }

    const float bk = b1[k];
    float4 xs4 = make_float4(ax0 + bk, ax1 + bk, ax2 + bk, ax3 + bk);
    float4 ys4 = make_float4(ay0, ay1, ay2, ay3);
    *(float4*)&xpbT[k * N_SAMP + r0] = xs4;  // 16B-aligned (r0 % 4 == 0)
    *(float4*)&ypT [k * N_SAMP + r0] = ys4;
}

// Kernel 2: pairwise relu-dot, row-sums of exp, diagonal, + ticket finalize.
//
// r7 post-mortem (model revision): ds_read_b128 moves 16 B/LANE (1 KB/instr,
// broadcasts free) -> LDS pipe is ~10 cy/k per CU, essentially free. The
// only hard floor is VALU issue: 96 cy/k/SIMD = 10.2 us, IDENTICAL for any
// accs-per-thread split. The knobs are per-k overhead VALU and waves/SIMD.
// 1 wave/SIMD never hid latency (r3/r5/r6/r7 all ~470 cy/k); 4 waves/SIMD
// did (r2: VALUBusy 57%) but burned 15 us on 64-bit global addressing.
// This version: 4 waves/SIMD AND zero-overhead addressing — thread tile
// 4j x 1i (4 accs), grid 16x64 = 1024 blocks = 4 blocks/CU, LDS tiles
// where a full 64-k pass spans 16 KB < the 16-bit ds-offset immediate:
// every k-loop read is base + compile-time offset, 0 address VALU.
__global__ __launch_bounds__(256, 4) void pair_fused(
    const float* __restrict__ ypT, const float* __restrict__ xpbT,
    const float* __restrict__ W2,
    float* __restrict__ S, float* __restrict__ T0s,
    const float* __restrict__ b2, float* __restrict__ out)
{
    __shared__ float xs[64][64];       // [kk][j] 16 KB
    __shared__ float ys[64][16];       // [kk][i]  4 KB
    __shared__ float wlds[HID];        //          1 KB

    const int tid = threadIdx.x;
    const int tj  = tid & 15;          // j sub-block 0..15
    const int ti  = tid >> 4;          // i row     0..15
    const int jb  = blockIdx.x * 64;
    const int ib  = blockIdx.y * 16;
    const int j0  = jb + tj * 4;
    const int i0  = ib + ti;
    const int tj4 = tj * 4;

    // W2 -> LDS once (64 float4 by threads 0..63); pass-0 barrier covers it.
    if (tid < 64) *(float4*)&wlds[tid * 4] = *(const float4*)&W2[tid * 4];

    float a0 = 0.f, a1 = 0.f, a2 = 0.f, a3 = 0.f;

    #pragma unroll 1
    for (int pass = 0; pass < 4; ++pass) {
        const int kof = pass << 6;             // 0,64,128,192
        if (pass) __syncthreads();             // LDS free before restage

        // Stage x panel: 1024 float4, 4 per thread. 16 consecutive lanes
        // cover one 256 B row -> coalesced global, contiguous LDS writes.
        #pragma unroll
        for (int s = 0; s < 4; ++s) {
            const int f  = s * 256 + tid;
            const int kk = f >> 4;
            const int q  = (f & 15) * 4;
            *(float4*)&xs[kk][q] = *(const float4*)&xpbT[(kof + kk) * N_SAMP + jb + q];
        }
        // Stage y panel: 256 float4, 1 per thread (4 lanes per 64 B row).
        {
            const int kk = tid >> 2;
            const int q  = (tid & 3) * 4;
            *(float4*)&ys[kk][q] = *(const float4*)&ypT[(kof + kk) * N_SAMP + ib + q];
        }
        __syncthreads();

        // 64 k, fully unrolled (~8.5 KB body; pass loop unroll 1 keeps it
        // I$-resident). Per 4-k group: 1 bcast b128 (w) + 4 b128 (x, 16
        // addrs 4x bcast) + 4 b32 (y, 4 addrs 16x bcast) — all at
        // compile-time immediate offsets — and 48 useful VALU.
        #pragma unroll
        for (int c = 0; c < 16; ++c) {
            const float4 wv = *(const float4*)&wlds[kof + c * 4];
            const float wu[4] = {wv.x, wv.y, wv.z, wv.w};
            #pragma unroll
            for (int u = 0; u < 4; ++u) {
                const int kk = c * 4 + u;
                const float4 xv = *(const float4*)&xs[kk][tj4];
                const float  yv = ys[kk][ti];
                a0 = fmaf(fmaxf(yv + xv.x, 0.f), wu[u], a0);
                a1 = fmaf(fmaxf(yv + xv.y, 0.f), wu[u], a1);
                a2 = fmaf(fmaxf(yv + xv.z, 0.f), wu[u], a2);
                a3 = fmaf(fmaxf(yv + xv.w, 0.f), wu[u], a3);
            }
        }
    }

    // Row sum of exp over this thread's 4 j's, then across the 16 tj lanes
    // (contiguous within a wave), then one atomic per i per block.
    // |acc| ~ O(1): exp without max-shift is safe in f32.
    {
        float e = __expf(a0) + __expf(a1) + __expf(a2) + __expf(a3);
        #pragma unroll
        for (int off = 8; off; off >>= 1) e += __shfl_xor(e, off, 16);
        if (tj == 0) atomicAdd(&S[i0], e);
    }

    // Diagonal (T0): i-range [bi*16,+16) inside j-range [bj*64,+64) iff
    // bj == bi>>2. Thread owns one i; d = i0 - j0 selects the acc.
    if ((int)blockIdx.x == (int)(blockIdx.y >> 2)) {
        const int d = i0 - j0;
        float dv = 0.f;
        if      (d == 0) dv = a0;
        else if (d == 1) dv = a1;
        else if (d == 2) dv = a2;
        else if (d == 3) dv = a3;
        #pragma unroll
        for (int off = 32; off; off >>= 1) dv += __shfl_xor(dv, off, 64);
        if ((tid & 63) == 0) atomicAdd(&T0s[0], dv);
    }

    // ---- last-block-done finalize (saves a 3rd kernel launch) ----
    // No spin loops: deadlock-free. Ticket re-zeroed by gemm_xy every
    // replay. All S/T0 traffic is device-scope atomics; read back via
    // atomicAdd(p, 0.f) so values come from the coherence point.
    int* lastflag = (int*)&ys[0][0];           // reuse LDS
    __threadfence();                           // my atomics visible device-wide
    __syncthreads();                           // all lanes' fences done
    if (tid == 0)
        *lastflag = (atomicAdd((unsigned*)&T0s[1], 1u) == 1023u);
    __syncthreads();
    if (!*lastflag) return;

    float* red = &xs[0][0];                    // reuse LDS for reduction
    float ls = 0.f;
    for (int i = tid; i < N_SAMP; i += 256)
        ls += logf(atomicAdd(&S[i], 0.f));
    #pragma unroll
    for (int off = 32; off; off >>= 1) ls += __shfl_xor(ls, off, 64);
    if ((tid & 63) == 0) red[tid >> 6] = ls;
    __syncthreads();

    if (tid == 0) {
        const float t0       = atomicAdd(&T0s[0], 0.f);
        const float lse_sum  = red[0] + red[1] + red[2] + red[3];
        const float t0_mean  = t0 / (float)N_SAMP + b2[0];
        const float lse_mean = lse_sum / (float)N_SAMP + b2[0]
                             - logf((float)N_SAMP);
        out[0] = t0_mean - lse_mean;
    }
}

extern "C" void kernel_launch(void* const* d_in, const int* in_sizes, int n_in,
                              void* d_out, int out_size, void* d_ws, size_t ws_size,
                              hipStream_t stream)
{
    const float* x  = (const float*)d_in[0];
    const float* y  = (const float*)d_in[1];
    const float* W1 = (const float*)d_in[2];
    const float* b1 = (const float*)d_in[3];
    const float* W2 = (const float*)d_in[4];
    const float* b2 = (const float*)d_in[5];

    float* ws   = (float*)d_ws;
    float* S    = ws;                          // 1024 floats
    float* T0s  = ws + 1024;                   // [0]=T0sum, [1]=ticket
    float* xpbT = ws + 2048;                   // [HID][N]
    float* ypT  = ws + 2048 + HID * N_SAMP;    // [HID][N]

    gemm_xy   <<<dim3(N_SAMP / 4), dim3(256), 0, stream>>>(x, y, W1, b1,
                                                           xpbT, ypT, S, T0s);
    pair_fused<<<dim3(16, 64),     dim3(256), 0, stream>>>(ypT, xpbT, W2,
                                                           S, T0s, b2,
                                                           (float*)d_out);
}

// Round 9
// 140.573 us; speedup vs baseline: 1.1320x; 1.1320x over previous
//
#include <hip/hip_runtime.h>

#define N_SAMP 1024
#define XD     128
#define HID    256

// ---------------------------------------------------------------------------
// Workspace layout (float indices):
//   [0, 1024)            S       per-i sum of exp(T1[i,j]) over j
//   [1024]               T0sum   sum over i of T1[i,i]  (diagonal, sans b2)
//   [1025]               ticket counter (uint bits), last-block-done
//   [2048, 2048+256K)    xpbT    (x @ W1x + b1)^T   [HID][N]  (k-major)
//   [next 256K)          ypT     (y @ W1y)^T        [HID][N]  (k-major)
// S/T0sum/ticket zeroed by gemm_xy (ws is poisoned 0xAA before every launch).
//
// r8 post-mortem: every inner-loop redesign (LDS staging, split-K, bigger/
// smaller register tiles, SWP, occupancy changes) regressed vs the round-0
// kernel (~38 us pair). This version restores the round-0 pair_lse EXACTLY
// and banks the one orthogonal, 4x-correctness-proven win: fusing the
// finalize via last-block ticket (3 dispatches -> 2, saving a launch gap
// + the finalize kernel).
// ---------------------------------------------------------------------------

// Kernel 1: the two small GEMMs, writing TRANSPOSED outputs. Thread k owns
// hidden unit k for 4 consecutive rows -> in k-major layout those 4 results
// are contiguous: one float4 store per array. Also zeroes S/T0sum/ticket.
__global__ __launch_bounds__(256) void gemm_xy(
    const float* __restrict__ x, const float* __restrict__ y,
    const float* __restrict__ W1, const float* __restrict__ b1,
    float* __restrict__ xpbT, float* __restrict__ ypT,
    float* __restrict__ S, float* __restrict__ T0sum)
{
    const int k  = threadIdx.x;        // hidden unit 0..255
    const int r0 = blockIdx.x * 4;     // 4 rows per block

    // Zero accumulators (256 blocks x 4 = 1024 S entries; block 0: T0+ticket).
    if (threadIdx.x < 4) S[blockIdx.x * 4 + threadIdx.x] = 0.f;
    if (blockIdx.x == 0 && threadIdx.x == 4) T0sum[0] = 0.f;
    if (blockIdx.x == 0 && threadIdx.x == 5) ((unsigned*)T0sum)[1] = 0u;

    float ax0 = 0.f, ax1 = 0.f, ax2 = 0.f, ax3 = 0.f;
    float ay0 = 0.f, ay1 = 0.f, ay2 = 0.f, ay3 = 0.f;

    #pragma unroll 4
    for (int d = 0; d < XD; ++d) {
        const float wx = W1[d * HID + k];            // coalesced over k
        const float wy = W1[(XD + d) * HID + k];
        ax0 = fmaf(x[(r0 + 0) * XD + d], wx, ax0);   // uniform -> s_load
        ax1 = fmaf(x[(r0 + 1) * XD + d], wx, ax1);
        ax2 = fmaf(x[(r0 + 2) * XD + d], wx, ax2);
        ax3 = fmaf(x[(r0 + 3) * XD + d], wx, ax3);
        ay0 = fmaf(y[(r0 + 0) * XD + d], wy, ay0);
        ay1 = fmaf(y[(r0 + 1) * XD + d], wy, ay1);
        ay2 = fmaf(y[(r0 + 2) * XD + d], wy, ay2);
        ay3 = fmaf(y[(r0 + 3) * XD + d], wy, ay3);
    }

    const float bk = b1[k];
    float4 xs = make_float4(ax0 + bk, ax1 + bk, ax2 + bk, ax3 + bk);
    float4 ys = make_float4(ay0, ay1, ay2, ay3);
    *(float4*)&xpbT[k * N_SAMP + r0] = xs;   // 16B-aligned (r0 % 4 == 0)
    *(float4*)&ypT [k * N_SAMP + r0] = ys;
}

// Kernel 2: pairwise relu-dot + exp row-sums (round-0 proven structure:
// pure global/L1 reads, no LDS in the k-loop, no syncthreads there.
// Block = 64 j-cols x 32 i-rows; thread = 4j x 2i = 8 accs. Per k:
// xT float4 (wave covers 256 contiguous B -> coalesced), yT float2
// (16-lane broadcast groups), W2[k] uniform -> s_load. 24 VALU per
// 2 vmem instr; grid 16x32 = 512 blocks = 2 blocks/CU = 2 waves/SIMD.)
// PLUS fused last-block-ticket finalize (saves the 3rd launch).
__global__ __launch_bounds__(256) void pair_lse(
    const float* __restrict__ ypT, const float* __restrict__ xpbT,
    const float* __restrict__ W2,
    float* __restrict__ S, float* __restrict__ T0s,
    const float* __restrict__ b2, float* __restrict__ out)
{
    const int tid = threadIdx.x;
    const int tj  = tid & 15;          // j sub-block 0..15
    const int ti  = tid >> 4;          // i sub-block 0..15
    const int bj  = blockIdx.x;        // 16 tiles of 64 j
    const int bi  = blockIdx.y;        // 32 tiles of 32 i
    const int j0  = bj * 64 + tj * 4;
    const int i0  = bi * 32 + ti * 2;

    float acc[2][4];
    #pragma unroll
    for (int a = 0; a < 2; ++a)
        #pragma unroll
        for (int b = 0; b < 4; ++b) acc[a][b] = 0.f;

    #pragma unroll 4
    for (int k = 0; k < HID; ++k) {
        const float4 xv = *(const float4*)&xpbT[k * N_SAMP + j0];
        const float2 yv = *(const float2*)&ypT [k * N_SAMP + i0];
        const float  w  = W2[k];                       // uniform -> s_load
        acc[0][0] = fmaf(fmaxf(yv.x + xv.x, 0.f), w, acc[0][0]);
        acc[0][1] = fmaf(fmaxf(yv.x + xv.y, 0.f), w, acc[0][1]);
        acc[0][2] = fmaf(fmaxf(yv.x + xv.z, 0.f), w, acc[0][2]);
        acc[0][3] = fmaf(fmaxf(yv.x + xv.w, 0.f), w, acc[0][3]);
        acc[1][0] = fmaf(fmaxf(yv.y + xv.x, 0.f), w, acc[1][0]);
        acc[1][1] = fmaf(fmaxf(yv.y + xv.y, 0.f), w, acc[1][1]);
        acc[1][2] = fmaf(fmaxf(yv.y + xv.z, 0.f), w, acc[1][2]);
        acc[1][3] = fmaf(fmaxf(yv.y + xv.w, 0.f), w, acc[1][3]);
    }

    // Per-i sums of exp over this thread's 4 j's, then across the 16 tj
    // lanes (contiguous within a wave), then one atomic per i per block.
    // |acc| ~ O(1): exp without max-shift is safe in f32.
    #pragma unroll
    for (int a = 0; a < 2; ++a) {
        float e = __expf(acc[a][0]) + __expf(acc[a][1])
                + __expf(acc[a][2]) + __expf(acc[a][3]);
        #pragma unroll
        for (int off = 8; off; off >>= 1) e += __shfl_xor(e, off, 16);
        if (tj == 0) atomicAdd(&S[i0 + a], e);
    }

    // Diagonal (T0): this block touches i==j iff bj == bi>>1.
    if (bj == (bi >> 1)) {
        float dv = 0.f;
        #pragma unroll
        for (int a = 0; a < 2; ++a)
            #pragma unroll
            for (int b = 0; b < 4; ++b)
                if (i0 + a == j0 + b) dv += acc[a][b];
        #pragma unroll
        for (int off = 32; off; off >>= 1) dv += __shfl_xor(dv, off, 64);
        if ((tid & 63) == 0) atomicAdd(&T0s[0], dv);
    }

    // ---- last-block-done finalize (saves a 3rd kernel launch) ----
    // Proven correct in r5-r8 (4/4 passes). No spin loops: deadlock-free.
    // Ticket re-zeroed by gemm_xy every replay. All S/T0 traffic is
    // device-scope atomics; read back via atomicAdd(p, 0.f) so values
    // come from the coherence point (per-XCD L2s not cross-coherent).
    __shared__ int   lastflag;
    __shared__ float red[4];

    __threadfence();                   // my atomics visible device-wide
    __syncthreads();                   // all lanes' fences done
    if (tid == 0)
        lastflag = (atomicAdd((unsigned*)&T0s[1], 1u) == 511u);  // 512 blocks
    __syncthreads();
    if (!lastflag) return;

    float ls = 0.f;
    for (int i = tid; i < N_SAMP; i += 256)
        ls += logf(atomicAdd(&S[i], 0.f));
    #pragma unroll
    for (int off = 32; off; off >>= 1) ls += __shfl_xor(ls, off, 64);
    if ((tid & 63) == 0) red[tid >> 6] = ls;
    __syncthreads();

    if (tid == 0) {
        const float t0       = atomicAdd(&T0s[0], 0.f);
        const float lse_sum  = red[0] + red[1] + red[2] + red[3];
        const float t0_mean  = t0 / (float)N_SAMP + b2[0];
        const float lse_mean = lse_sum / (float)N_SAMP + b2[0]
                             - logf((float)N_SAMP);
        out[0] = t0_mean - lse_mean;
    }
}

extern "C" void kernel_launch(void* const* d_in, const int* in_sizes, int n_in,
                              void* d_out, int out_size, void* d_ws, size_t ws_size,
                              hipStream_t stream)
{
    const float* x  = (const float*)d_in[0];
    const float* y  = (const float*)d_in[1];
    const float* W1 = (const float*)d_in[2];
    const float* b1 = (const float*)d_in[3];
    const float* W2 = (const float*)d_in[4];
    const float* b2 = (const float*)d_in[5];

    float* ws   = (float*)d_ws;
    float* S    = ws;                          // 1024 floats
    float* T0s  = ws + 1024;                   // [0]=T0sum, [1]=ticket
    float* xpbT = ws + 2048;                   // [HID][N]
    float* ypT  = ws + 2048 + HID * N_SAMP;    // [HID][N]

    gemm_xy <<<dim3(N_SAMP / 4), dim3(256), 0, stream>>>(x, y, W1, b1,
                                                         xpbT, ypT, S, T0s);
    pair_lse<<<dim3(16, 32),     dim3(256), 0, stream>>>(ypT, xpbT, W2,
                                                         S, T0s, b2,
                                                         (float*)d_out);
}